// Round 8
// baseline (177.455 us; speedup 1.0000x reference)
//
#include <hip/hip_runtime.h>
#include <cstdint>

// Chamfer distance, B=8, N=M=4096, D=128, f32 in, scalar f32 out.
// R20: rt=8 register-blocking attack. Ledger model: total = ~45us fixed +
// kernel sum -> main loop is the lever. Counters show NO saturated pipe and
// Occupancy ~15-19% (~1.5 blocks/CU): VGPR_Count 108 EXCLUDES the 64 AGPR
// accumulators (108+64=172 > 128-granule -> 2 waves/SIMD cap). Can't add
// waves -> add work per wave: each wave owns 128 rows (rt=8), so each LDS
// B-fragment read feeds 8 MFMAs (was 4): LDS:MFMA per CU-tile 1540:1280cy
// (was 3084:1280), barriers per output halve, colmin contention halves
// (XG=8). Block=512 rows, GRID=512. Single-arg LB(256): compiler picks regs
// freely (~250 -> 2 waves/EU if it fits, 1 if not; no forced spill).
// Tail reduce: unroll 16 (16 float4 loads in flight, latency-pipelined).
// Protocol unchanged from R19 (fence-free release, one acquire in last blk).
// Workspace: xb(8M) yb(8M) x2(128K) y2(128K) minbuf(256K) counter(4B).

#define B_   8
#define N_   4096
#define M_   4096
#define D_   128
#define TPB  8               // y-tiles (64 cols) per block -> 512-col chunk
#define ROWS_PB 512          // x-rows per block = 4 waves * 128
#define XG   (N_ / ROWS_PB)  // 8 x-groups
#define CHUNKS (M_ / (TPB * 64))   // 8 y-chunks
#define GRID (B_ * XG * CHUNKS)    // 512 blocks
#define RT   8               // row-tiles of 16 per wave

typedef __bf16 bf16x8 __attribute__((ext_vector_type(8)));
typedef float  f32x4  __attribute__((ext_vector_type(4)));
typedef unsigned int u32;

static __device__ __forceinline__ unsigned short f2bf(float f) {
  unsigned u = __float_as_uint(f);
  u += 0x7FFFu + ((u >> 16) & 1u);   // round-to-nearest-even
  return (unsigned short)(u >> 16);
}
static __device__ __forceinline__ void gld16(void* lds, const void* g) {
  __builtin_amdgcn_global_load_lds(
      (const __attribute__((address_space(1))) void*)g,
      (__attribute__((address_space(3))) void*)lds, 16, 0, 0);
}

// prep: wave handles 2 rows (32 lanes x float4 each). xb = bf16(-2x),
// yb = bf16(y), fp32 norms. Also seeds minbuf=+INF and counter=0.
__global__ __launch_bounds__(256) void prep(
    const float* __restrict__ x, const float* __restrict__ y,
    unsigned short* __restrict__ xb, unsigned short* __restrict__ yb,
    float* __restrict__ x2, float* __restrict__ y2,
    float* __restrict__ minbuf, int* __restrict__ counter)
{
  const int ROWS = B_ * N_;
  const int flat = blockIdx.x * 256 + threadIdx.x;
  if (flat < 2 * B_ * N_) minbuf[flat] = __uint_as_float(0x7F800000u);
  if (flat == 0) *counter = 0;

  int gw   = flat >> 6;                      // wave id
  int lane = threadIdx.x & 63;
  int half = lane >> 5, sub = lane & 31;
  int row2 = gw * 2 + half;                  // 0 .. 2*ROWS-1 (x rows then y rows)
  bool isx = row2 < ROWS;
  const float* src; unsigned short* dst; float* nrm; int row;
  if (isx) { src = x; dst = xb; nrm = x2; row = row2; }
  else     { src = y; dst = yb; nrm = y2; row = row2 - ROWS; }
  size_t base = (size_t)row * D_ + sub * 4;
  float4 v = *(const float4*)(src + base);
  float sx = isx ? -2.0f : 1.0f;
  u32 p0 = (u32)f2bf(sx * v.x) | ((u32)f2bf(sx * v.y) << 16);
  u32 p1 = (u32)f2bf(sx * v.z) | ((u32)f2bf(sx * v.w) << 16);
  *(uint2*)(dst + base) = make_uint2(p0, p1);
  float s = v.x * v.x + v.y * v.y + v.z * v.z + v.w * v.w;
  #pragma unroll
  for (int m = 1; m < 32; m <<= 1) s += __shfl_xor(s, m, 64);
  if (sub == 0) nrm[row] = s;
}

// Fragment layouts (HW-verified):
//   A/B operand: lane holds elems [row=lane&15][k=(lane>>4)*8 + 0..7]
//   C/D:         lane reg r holds [row=(lane>>4)*4+r][col=lane&15]
// acc init = x2_i (xb holds bf16(-2x)), so a = x2_i - 2<x,y>; s = a + y2_j.
// LDS y layout: row r (256B), logical 16B-chunk c at physical chunk c^(r&15).
__global__ __launch_bounds__(256) void chamfer(
    const unsigned short* __restrict__ xb, const unsigned short* __restrict__ yb,
    const float* __restrict__ x2, const float* __restrict__ y2,
    float* __restrict__ minbuf, int* __restrict__ counter,
    float* __restrict__ out)
{
  __shared__ unsigned short ys[2 * 8192];    // two 16 KB swizzled y-tiles ONLY
  __shared__ int amLast;
  __shared__ float red[4];

  float* rowmin = minbuf;                    // [B*N]
  float* colmin = minbuf + B_ * N_;          // [B*M]

  const int tid  = threadIdx.x;
  const int wave = tid >> 6;                 // 0..3
  const int lane = tid & 63;
  const int quad = lane >> 4;
  const int l15  = lane & 15;

  const int id    = blockIdx.x;        // 0..511
  const int b     = id & 7;
  const int xg    = (id >> 3) & (XG - 1);
  const int chunk = id >> 6;           // 0..7
  const int n0    = xg * ROWS_PB;
  const int mc0   = chunk * (TPB * 64);

  // DMA: 16KB tile, 4 gld16/lane: instr i covers bytes (wave*4+i)*1024+lane*16.
  int srcoff[4], ldsoff[4];
  #pragma unroll
  for (int i = 0; i < 4; ++i) {
    int p  = (wave * 4 + i) * 1024 + lane * 16;
    int r  = p >> 8;                 // y row 0..63
    int pc = (p >> 4) & 15;          // physical chunk
    int c  = pc ^ (r & 15);          // logical chunk
    srcoff[i] = r * D_ + c * 8;      // elements
    ldsoff[i] = (wave * 4 + i) * 1024;
  }

  // preload tile 0
  {
    const unsigned short* src = yb + ((size_t)b * M_ + mc0) * D_;
    #pragma unroll
    for (int i = 0; i < 4; ++i) gld16((char*)ys + ldsoff[i], src + srcoff[i]);
  }

  // A fragments: direct global->register, rows n0 + wave*128 + rt*16 + l15.
  bf16x8 afrag[4][RT];   // [kb][rt]  = 128 VGPR
  const size_t xrow0 = (size_t)b * N_ + n0 + wave * 128;
  #pragma unroll
  for (int kb = 0; kb < 4; ++kb)
    #pragma unroll
    for (int rt = 0; rt < RT; ++rt)
      afrag[kb][rt] = *(const bf16x8*)(xb + (xrow0 + rt * 16 + l15) * D_ + kb * 32 + quad * 8);

  // x2 for this wave's 32 output rows (t-invariant), as f32x4 for acc init
  f32x4 xvv[RT];
  #pragma unroll
  for (int rt = 0; rt < RT; ++rt)
    #pragma unroll
    for (int r = 0; r < 4; ++r)
      xvv[rt][r] = x2[xrow0 + rt * 16 + quad * 4 + r];

  const float FINF = __uint_as_float(0x7F800000u);
  float rmin2[RT][4];
  #pragma unroll
  for (int rt = 0; rt < RT; ++rt)
    #pragma unroll
    for (int r = 0; r < 4; ++r) rmin2[rt][r] = FINF;

  #pragma unroll 1
  for (int t = 0; t < TPB; ++t) {
    const int m0 = mc0 + t * 64;
    const int d  = (t & 1) * 16384;    // current buffer byte offset
    __syncthreads();  // drains DMA for buf d (prefetch had a full iteration);
                      // fences prior-buffer reads

    if (t + 1 < TPB) {  // prefetch next tile into the other buffer ASAP
      const unsigned short* src = yb + ((size_t)b * M_ + m0 + 64) * D_;
      char* dst = (char*)ys + (16384 - d);
      #pragma unroll
      for (int i = 0; i < 4; ++i) gld16(dst + ldsoff[i], src + srcoff[i]);
    }

    // per-tile y^2: 4 per-lane scalars (16-lane coalesced, quad-broadcast)
    float y2r[4];
    #pragma unroll
    for (int ct = 0; ct < 4; ++ct)
      y2r[ct] = y2[(size_t)b * M_ + m0 + ct * 16 + l15];

    #pragma unroll
    for (int ct = 0; ct < 4; ++ct) {
      f32x4 a[RT];
      #pragma unroll
      for (int rt = 0; rt < RT; ++rt) a[rt] = xvv[rt];   // acc init = x2
      #pragma unroll
      for (int kb = 0; kb < 4; ++kb) {                   // interleaved bfr
        const int row = ct * 16 + l15;
        const int pcB = (kb * 4 + quad) ^ l15;           // swizzled chunk
        bf16x8 bfr = *(const bf16x8*)((const char*)ys + d + row * 256 + pcB * 16);
        #pragma unroll
        for (int rt = 0; rt < RT; ++rt)                  // 8 MFMA per LDS read
          a[rt] = __builtin_amdgcn_mfma_f32_16x16x32_bf16(afrag[kb][rt], bfr, a[rt], 0, 0, 0);
      }
      // epilogue: s = d^2, row-min partials in-register;
      // col-min: fold 32 regs, 2x shfl_xor folds quads -> wave min -> atomicMin
      float yv = y2r[ct];
      float cm = FINF;
      #pragma unroll
      for (int rt = 0; rt < RT; ++rt) {
        float s0 = a[rt][0] + yv; rmin2[rt][0] = fminf(rmin2[rt][0], s0);
        float s1 = a[rt][1] + yv; rmin2[rt][1] = fminf(rmin2[rt][1], s1);
        float s2 = a[rt][2] + yv; rmin2[rt][2] = fminf(rmin2[rt][2], s2);
        float s3 = a[rt][3] + yv; rmin2[rt][3] = fminf(rmin2[rt][3], s3);
        cm = fminf(cm, fminf(fminf(s0, s1), fminf(s2, s3)));
      }
      cm = fminf(cm, __shfl_xor(cm, 16, 64));
      cm = fminf(cm, __shfl_xor(cm, 32, 64));
      if (quad == 0)
        atomicMin((int*)(colmin + (size_t)b * M_ + m0 + ct * 16 + l15),
                  __float_as_int(cm));
    }
  }

  // Row mins over this chunk: reduce across 16 col-lanes, then atomicMin.
  #pragma unroll
  for (int rt = 0; rt < RT; ++rt) {
    #pragma unroll
    for (int r = 0; r < 4; ++r) {
      float v = rmin2[rt][r];
      v = fminf(v, __shfl_xor(v, 1, 64));
      v = fminf(v, __shfl_xor(v, 2, 64));
      v = fminf(v, __shfl_xor(v, 4, 64));
      v = fminf(v, __shfl_xor(v, 8, 64));
      if (l15 == 0)
        atomicMin((int*)(rowmin + xrow0 + rt * 16 + quad * 4 + r),
                  __float_as_int(v));
    }
  }

  // ---- completion protocol, fence-free release (R19-proven) ----
  __syncthreads();                 // vmcnt(0): all this block's atomics ack'd
  if (tid == 0)
    amLast = (__hip_atomic_fetch_add(counter, 1, __ATOMIC_RELAXED,
                                     __HIP_MEMORY_SCOPE_AGENT) == GRID - 1);
  __syncthreads();
  if (amLast) {
    __threadfence();               // acquire (once): invalidate L1/L2 so plain
                                   // loads see the coherence point
    const float4* mb4 = (const float4*)minbuf;
    float s = 0.0f;
    #pragma unroll 16              // 16 independent loads in flight per thread
    for (int i = tid; i < (2 * B_ * N_) / 4; i += 256) {
      float4 v = mb4[i];
      s += sqrtf(fmaxf(v.x, 0.0f)) + sqrtf(fmaxf(v.y, 0.0f))
         + sqrtf(fmaxf(v.z, 0.0f)) + sqrtf(fmaxf(v.w, 0.0f));
    }
    #pragma unroll
    for (int m = 1; m < 64; m <<= 1) s += __shfl_xor(s, m, 64);
    if (lane == 0) red[wave] = s;
    __syncthreads();
    if (tid == 0)
      *out = (red[0] + red[1] + red[2] + red[3]) / (float)(B_ * N_);
  }
}

extern "C" void kernel_launch(void* const* d_in, const int* in_sizes, int n_in,
                              void* d_out, int out_size, void* d_ws, size_t ws_size,
                              hipStream_t stream)
{
  const float* x = (const float*)d_in[0];
  const float* y = (const float*)d_in[1];
  char* ws = (char*)d_ws;

  unsigned short* xb = (unsigned short*)(ws);               // 8 MB
  unsigned short* yb = (unsigned short*)(ws + (8u << 20));  // 8 MB
  float* x2     = (float*)(ws + (16u << 20));               // 128 KB
  float* y2     = (float*)(ws + (16u << 20) + (1u << 17));  // 128 KB
  float* minbuf = (float*)(ws + (16u << 20) + (2u << 17));  // 256 KB (rowmin++colmin)
  int*   cnt    = (int*)  (ws + (16u << 20) + (4u << 17));  // 4 B
  float* outf = (float*)d_out;

  prep<<<(B_ * N_) / 4, 256, 0, stream>>>(x, y, xb, yb, x2, y2, minbuf, cnt);

  chamfer<<<GRID, 256, 0, stream>>>(xb, yb, x2, y2, minbuf, cnt, outf);
}